// Round 8
// baseline (1665.527 us; speedup 1.0000x reference)
//
#include <hip/hip_runtime.h>
#include <math.h>

#define EMBED 1024
#define NHEAD 16
#define HDIM  64
#define MAXPOS 512
#define TOPK  32
#define BB    8
#define TTT   512
#define BT    (BB*TTT)   // 4096 tokens
#define SCORE_EPS 1e-4f

// ---------------------------------------------------------------------------
// Q+K projection GEMM, fp64 accumulation. Round-6 verbatim.
// blockIdx.y 0..15 -> Q (Wq,bq,outq), 16..31 -> K (Wk,bk,outk).
// ---------------------------------------------------------------------------
__global__ __launch_bounds__(256, 2)
void gemm_qk_f64(const float* __restrict__ A,
                 const float* __restrict__ Wq, const float* __restrict__ bq_,
                 const float* __restrict__ Wk, const float* __restrict__ bk_,
                 float* __restrict__ outq, float* __restrict__ outk)
{
    __shared__ float As[16][132];
    __shared__ float Bs[16][68];
    const int t  = threadIdx.x;
    const int mb = blockIdx.x;        // 0..31  rows mb*128
    const int yy = blockIdx.y;        // 0..31
    const int nb = yy & 15;           // head
    const float* __restrict__ W    = (yy < 16) ? Wq  : Wk;
    const float* __restrict__ bias = (yy < 16) ? bq_ : bk_;
    float*                    out  = (yy < 16) ? outq : outk;
    const int tr = t >> 4, tc = t & 15;

    double acc[8][4] = {};

    for (int kt = 0; kt < 1024; kt += 16) {
        #pragma unroll
        for (int i = 0; i < 2; i++) {
            int L   = t + i * 256;
            int row = L >> 2;
            int cg  = (L & 3) * 4;
            float4 a4 = *(const float4*)&A[(size_t)(mb*128 + row)*1024 + kt + cg];
            As[cg+0][row] = a4.x; As[cg+1][row] = a4.y;
            As[cg+2][row] = a4.z; As[cg+3][row] = a4.w;
        }
        {
            int row = t >> 2, cg = (t & 3) * 4;
            float4 b4 = *(const float4*)&W[(size_t)(nb*64 + row)*1024 + kt + cg];
            Bs[cg+0][row] = b4.x; Bs[cg+1][row] = b4.y;
            Bs[cg+2][row] = b4.z; Bs[cg+3][row] = b4.w;
        }
        __syncthreads();
        #pragma unroll
        for (int kk = 0; kk < 16; kk++) {
            float a[8], bv[4];
            *(float4*)&a[0]  = *(const float4*)&As[kk][tr*8];
            *(float4*)&a[4]  = *(const float4*)&As[kk][tr*8+4];
            *(float4*)&bv[0] = *(const float4*)&Bs[kk][tc*4];
            double bd[4] = {(double)bv[0], (double)bv[1], (double)bv[2], (double)bv[3]};
            #pragma unroll
            for (int i = 0; i < 8; i++) {
                double ad = (double)a[i];
                #pragma unroll
                for (int j = 0; j < 4; j++)
                    acc[i][j] = fma(ad, bd[j], acc[i][j]);
            }
        }
        __syncthreads();
    }

    #pragma unroll
    for (int i = 0; i < 8; i++) {
        int token = mb*128 + tr*8 + i;
        int b  = token >> 9, tt = token & 511;
        int c0 = nb*64 + tc*4;
        float4 v;
        v.x = (float)(acc[i][0] + (double)bias[c0+0]);
        v.y = (float)(acc[i][1] + (double)bias[c0+1]);
        v.z = (float)(acc[i][2] + (double)bias[c0+2]);
        v.w = (float)(acc[i][3] + (double)bias[c0+3]);
        *(float4*)&out[(((size_t)b*NHEAD + nb)*TTT + tt)*HDIM + tc*4] = v;
    }
}

// ---------------------------------------------------------------------------
// fp32 GEMM (NT) for V projection (scatter=1) and O projection (scatter=0).
// Round-6 verbatim.
// ---------------------------------------------------------------------------
__global__ __launch_bounds__(256, 2)
void gemm_nt(const float* __restrict__ A, const float* __restrict__ W,
             const float* __restrict__ bias, float* __restrict__ out,
             int scatter)
{
    __shared__ float As[16][132];
    __shared__ float Bs[16][132];
    const int t  = threadIdx.x;
    const int mb = blockIdx.x;
    const int nb = blockIdx.y;
    const int tr = t >> 4, tc = t & 15;

    float acc[8][8] = {};

    for (int kt = 0; kt < 1024; kt += 16) {
        #pragma unroll
        for (int i = 0; i < 2; i++) {
            int L   = t + i * 256;
            int row = L >> 2;
            int cg  = (L & 3) * 4;
            float4 a4 = *(const float4*)&A[(size_t)(mb*128 + row)*1024 + kt + cg];
            As[cg+0][row] = a4.x; As[cg+1][row] = a4.y;
            As[cg+2][row] = a4.z; As[cg+3][row] = a4.w;
            float4 b4 = *(const float4*)&W[(size_t)(nb*128 + row)*1024 + kt + cg];
            Bs[cg+0][row] = b4.x; Bs[cg+1][row] = b4.y;
            Bs[cg+2][row] = b4.z; Bs[cg+3][row] = b4.w;
        }
        __syncthreads();
        #pragma unroll
        for (int kk = 0; kk < 16; kk++) {
            float a[8], bv[8];
            *(float4*)&a[0]  = *(const float4*)&As[kk][tr*8];
            *(float4*)&a[4]  = *(const float4*)&As[kk][tr*8+4];
            *(float4*)&bv[0] = *(const float4*)&Bs[kk][tc*8];
            *(float4*)&bv[4] = *(const float4*)&Bs[kk][tc*8+4];
            #pragma unroll
            for (int i = 0; i < 8; i++)
                #pragma unroll
                for (int j = 0; j < 8; j++)
                    acc[i][j] = fmaf(a[i], bv[j], acc[i][j]);
        }
        __syncthreads();
    }

    if (scatter) {
        #pragma unroll
        for (int i = 0; i < 8; i++) {
            int token = mb*128 + tr*8 + i;
            int b  = token >> 9, tt = token & 511;
            #pragma unroll
            for (int jg = 0; jg < 2; jg++) {
                int c = nb*128 + tc*8 + jg*4;
                int h = c >> 6, d = c & 63;
                float4 v;
                v.x = acc[i][jg*4+0] + bias[c+0];
                v.y = acc[i][jg*4+1] + bias[c+1];
                v.z = acc[i][jg*4+2] + bias[c+2];
                v.w = acc[i][jg*4+3] + bias[c+3];
                *(float4*)&out[(((size_t)b*NHEAD + h)*TTT + tt)*HDIM + d] = v;
            }
        }
    } else {
        #pragma unroll
        for (int i = 0; i < 8; i++) {
            int token = mb*128 + tr*8 + i;
            #pragma unroll
            for (int jg = 0; jg < 2; jg++) {
                int c = nb*128 + tc*8 + jg*4;
                float4 v;
                v.x = acc[i][jg*4+0] + bias[c+0];
                v.y = acc[i][jg*4+1] + bias[c+1];
                v.z = acc[i][jg*4+2] + bias[c+2];
                v.w = acc[i][jg*4+3] + bias[c+3];
                *(float4*)&out[(size_t)token*1024 + c] = v;
            }
        }
    }
}

// ---------------------------------------------------------------------------
// Attention core — round-6 structure (128-col K tiles, 8 waves x 4 rows),
// with: (1) launch_bounds(512,2) so the allocator can use >64 VGPR without
// spilling (spill scratch is the suspected 2-block/CU residency cap);
// (2) fp32 fast-path scores + eps-guard: top-k decisions provably match the
// fp64 path unless another score lies within SCORE_EPS of the threshold
// (fp32 dot worst error ~4e-6, eps = 1e-4 => 25x margin); flagged rows
// (~3%) are recomputed fully in fp64 (d-ascending, bias in fp64, single
// rounding — identical to rounds 3-7) and their top-k redone.
// ---------------------------------------------------------------------------
__global__ __launch_bounds__(512, 2)
void attn_kernel(const float* __restrict__ qb, const float* __restrict__ kb,
                 const float* __restrict__ vb, const float* __restrict__ gates,
                 const float* __restrict__ relb, float* __restrict__ aout)
{
    __shared__ float qs[32][68];                        // 8.7 KB (padded)
    __shared__ union {
        float ks[128][68];                              // 34.8 KB  K-tile [col][d]
        struct { float w[32][64]; unsigned short c[32][64]; } sp;  // 12 KB
    } u;

    const int t    = threadIdx.x;
    const int lane = t & 63, wv = t >> 6;               // 8 waves
    const int qt   = blockIdx.x;        // 0..15
    const int bh   = blockIdx.y;        // 0..127
    const int h    = bh & 15, b = bh >> 4;
    const int qrow_g = qt * 32;
    const int r0   = wv * 4;            // this wave's 4 block-local rows

    const float* qbase = qb + ((size_t)bh*TTT + qrow_g)*HDIM;
    const float* kbase = kb + (size_t)bh*TTT*HDIM;
    const float* vbase = vb + (size_t)bh*TTT*HDIM;

    // ---- load Q tile (32x64) as fp32 ----
    {
        int row = t >> 4, cg = (t & 15) * 4;
        *(float4*)&qs[row][cg] = *(const float4*)&qbase[(size_t)row*HDIM + cg];
    }

    float sc[4][8];                     // scores: sc[i][j] = S[r0+i][lane+64j]

    // ---- scores: 4 K-tiles of 128 cols, fp32 fast path ----
    #pragma unroll
    for (int ktile = 0; ktile < 4; ktile++) {
        __syncthreads();                // protects u.ks (and qs on first iter)
        #pragma unroll
        for (int i = 0; i < 4; i++) {   // stage K tile as [col][d]
            int L   = t + i * 512;
            int col = L >> 4, dg = (L & 15) * 4;
            *(float4*)&u.ks[col][dg] =
                *(const float4*)&kbase[(size_t)(ktile*128 + col)*HDIM + dg];
        }
        __syncthreads();

        float acc[4][2] = {};
        #pragma unroll 4
        for (int d = 0; d < 64; d += 4) {
            float4 k0 = *(const float4*)&u.ks[lane][d];
            float4 k1 = *(const float4*)&u.ks[lane+64][d];
            #pragma unroll
            for (int i = 0; i < 4; i++) {
                float4 q4 = *(const float4*)&qs[r0+i][d];   // broadcast read
                acc[i][0] = fmaf(q4.x, k0.x, acc[i][0]);
                acc[i][0] = fmaf(q4.y, k0.y, acc[i][0]);
                acc[i][0] = fmaf(q4.z, k0.z, acc[i][0]);
                acc[i][0] = fmaf(q4.w, k0.w, acc[i][0]);
                acc[i][1] = fmaf(q4.x, k1.x, acc[i][1]);
                acc[i][1] = fmaf(q4.y, k1.y, acc[i][1]);
                acc[i][1] = fmaf(q4.z, k1.z, acc[i][1]);
                acc[i][1] = fmaf(q4.w, k1.w, acc[i][1]);
            }
        }
        #pragma unroll
        for (int i = 0; i < 4; i++) {
            int rg = qrow_g + r0 + i;
            #pragma unroll
            for (int s01 = 0; s01 < 2; s01++) {
                int c = ktile*128 + lane + 64*s01;
                sc[i][2*ktile+s01] = acc[i][s01]*0.125f +
                                     relb[(size_t)(c - rg + 511)*NHEAD + h];
            }
        }
    }
    __syncthreads();                    // u.ks dead; u.sp may now be written

    // ---- top-32 threshold: 32 extract-max iterations, 4 rows interleaved ----
    float val[4][8];
    #pragma unroll
    for (int i = 0; i < 4; i++)
        #pragma unroll
        for (int j = 0; j < 8; j++) val[i][j] = sc[i][j];

    float rowmax[4], thresh[4];
    #pragma unroll 1
    for (int it = 0; it < TOPK; it++) {
        #pragma unroll
        for (int rr = 0; rr < 4; rr++) {
            float lm = val[rr][0];
            #pragma unroll
            for (int j = 1; j < 8; j++) lm = fmaxf(lm, val[rr][j]);
            float m = lm;
            #pragma unroll
            for (int off = 32; off >= 1; off >>= 1)
                m = fmaxf(m, __shfl_xor(m, off));
            if (it == 0) rowmax[rr] = m;
            thresh[rr] = m;
            unsigned long long ball = __ballot(lm == m);
            int first = __ffsll(ball) - 1;
            if (lane == first) {        // zap exactly one instance of m
                bool done = false;
                #pragma unroll
                for (int j = 0; j < 8; j++)
                    if (!done && val[rr][j] == m) { val[rr][j] = -__builtin_inff(); done = true; }
            }
        }
    }

    // ---- per row: eps-guard (+ rare fp64 fixup), softmax, compaction, PV ----
    const float gate = gates[h];
    #pragma unroll 1
    for (int rr = 0; rr < 4; rr++) {
        int row = r0 + rr;

        // guard: if any OTHER score lies within eps of the threshold, the fp32
        // ranking may disagree with fp64 -> recompute this row in fp64.
        int band = 0;
        #pragma unroll
        for (int j = 0; j < 8; j++) {
            bool inb = fabsf(sc[rr][j] - thresh[rr]) <= SCORE_EPS;
            band += __popcll(__ballot(inb));
        }
        if (band >= 2) {
            // ---- fp64 fixup: recompute all 512 scores of this row ----
            int rg = qrow_g + row;
            #pragma unroll 1
            for (int j = 0; j < 8; j++) {
                int c = lane + 64*j;
                const float* kc = kbase + (size_t)c*HDIM;
                double a = 0.0;
                #pragma unroll 4
                for (int d = 0; d < 64; d += 4) {
                    float4 kv = *(const float4*)&kc[d];
                    float4 q4 = *(const float4*)&qs[row][d];
                    a = fma((double)q4.x, (double)kv.x, a);
                    a = fma((double)q4.y, (double)kv.y, a);
                    a = fma((double)q4.z, (double)kv.z, a);
                    a = fma((double)q4.w, (double)kv.w, a);
                }
                sc[rr][j] = (float)(a*0.125 +
                            (double)relb[(size_t)(c - rg + 511)*NHEAD + h]);
            }
            // redo top-32 for this row on the fp64-grade scores
            float v2[8];
            #pragma unroll
            for (int j = 0; j < 8; j++) v2[j] = sc[rr][j];
            #pragma unroll 1
            for (int it = 0; it < TOPK; it++) {
                float lm = v2[0];
                #pragma unroll
                for (int j = 1; j < 8; j++) lm = fmaxf(lm, v2[j]);
                float m = lm;
                #pragma unroll
                for (int off = 32; off >= 1; off >>= 1)
                    m = fmaxf(m, __shfl_xor(m, off));
                if (it == 0) rowmax[rr] = m;
                thresh[rr] = m;
                unsigned long long ball = __ballot(lm == m);
                int first = __ffsll(ball) - 1;
                if (lane == first) {
                    bool done = false;
                    #pragma unroll
                    for (int j = 0; j < 8; j++)
                        if (!done && v2[j] == m) { v2[j] = -__builtin_inff(); done = true; }
                }
            }
        }

        // ---- softmax weights ----
        float w[8];
        float sum = 0.f;
        #pragma unroll
        for (int j = 0; j < 8; j++) {
            float sv = sc[rr][j];
            float wv2 = (sv >= thresh[rr]) ? __expf(sv - rowmax[rr]) : 0.f;
            w[j] = wv2;
            sum += wv2;
        }
        #pragma unroll
        for (int off = 32; off >= 1; off >>= 1)
            sum += __shfl_xor(sum, off);
        float rscale = gate / sum;

        // ---- compact kept entries (col ascending: j-major, lane-minor) ----
        int n = 0;
        #pragma unroll
        for (int j = 0; j < 8; j++) {
            bool keep = (sc[rr][j] >= thresh[rr]);
            unsigned long long mask = __ballot(keep);
            int pos = n + __popcll(mask & ((1ull << lane) - 1ull));
            if (keep && pos < 64) {
                u.sp.c[row][pos] = (unsigned short)(lane + 64*j);
                u.sp.w[row][pos] = w[j];
            }
            n += __popcll(mask);
        }
        if (n > 64) n = 64;

        // ---- sparse PV: lane == d; entries ascending == k-ascending order ----
        float o = 0.f;
        int e = 0;
        for (; e + 4 <= n; e += 4) {
            int   c0 = u.sp.c[row][e],   c1 = u.sp.c[row][e+1];
            int   c2 = u.sp.c[row][e+2], c3 = u.sp.c[row][e+3];
            float w0 = u.sp.w[row][e],   w1 = u.sp.w[row][e+1];
            float w2 = u.sp.w[row][e+2], w3 = u.sp.w[row][e+3];
            float v0 = vbase[(size_t)c0*HDIM + lane];
            float v1 = vbase[(size_t)c1*HDIM + lane];
            float v2_ = vbase[(size_t)c2*HDIM + lane];
            float v3 = vbase[(size_t)c3*HDIM + lane];
            o = fmaf(w0, v0, o);
            o = fmaf(w1, v1, o);
            o = fmaf(w2, v2_, o);
            o = fmaf(w3, v3, o);
        }
        for (; e < n; e++) {
            int   c = u.sp.c[row][e];
            float wv2 = u.sp.w[row][e];
            o = fmaf(wv2, vbase[(size_t)c*HDIM + lane], o);
        }

        aout[((size_t)(b*TTT + qrow_g + row))*EMBED + h*HDIM + lane] = o * rscale;
    }
}

// ---------------------------------------------------------------------------
extern "C" void kernel_launch(void* const* d_in, const int* in_sizes, int n_in,
                              void* d_out, int out_size, void* d_ws, size_t ws_size,
                              hipStream_t stream) {
    const float* x     = (const float*)d_in[0];
    const float* Wq    = (const float*)d_in[1];
    const float* bq    = (const float*)d_in[2];
    const float* Wk    = (const float*)d_in[3];
    const float* bk    = (const float*)d_in[4];
    const float* Wv    = (const float*)d_in[5];
    const float* bv    = (const float*)d_in[6];
    const float* Wo    = (const float*)d_in[7];
    const float* bo    = (const float*)d_in[8];
    const float* gates = (const float*)d_in[9];
    const float* relb  = (const float*)d_in[10];
    float* out = (float*)d_out;

    const size_t SZ = (size_t)BT * EMBED;   // 4,194,304 floats
    float* qb = (float*)d_ws;
    float* kb = qb + SZ;
    float* vb = kb + SZ;
    float* ab = vb + SZ;

    gemm_qk_f64<<<dim3(32,32), dim3(256), 0, stream>>>(x, Wq, bq, Wk, bk, qb, kb);
    gemm_nt<<<dim3(32,8), dim3(256), 0, stream>>>(x, Wv, bv, vb, 1);
    attn_kernel<<<dim3(16,128), dim3(512), 0, stream>>>(qb, kb, vb, gates, relb, ab);
    gemm_nt<<<dim3(32,8), dim3(256), 0, stream>>>(ab, Wo, bo, out, 0);
}

// Round 9
// 1253.915 us; speedup vs baseline: 1.3283x; 1.3283x over previous
//
#include <hip/hip_runtime.h>
#include <math.h>

#define EMBED 1024
#define NHEAD 16
#define HDIM  64
#define MAXPOS 512
#define TOPK  32
#define BB    8
#define TTT   512
#define BT    (BB*TTT)   // 4096 tokens
#define SCORE_EPS 1e-4f

// ---------------------------------------------------------------------------
// Q+K projection GEMM, fp64 accumulation. Round-6 verbatim.
// blockIdx.y 0..15 -> Q (Wq,bq,outq), 16..31 -> K (Wk,bk,outk).
// ---------------------------------------------------------------------------
__global__ __launch_bounds__(256, 2)
void gemm_qk_f64(const float* __restrict__ A,
                 const float* __restrict__ Wq, const float* __restrict__ bq_,
                 const float* __restrict__ Wk, const float* __restrict__ bk_,
                 float* __restrict__ outq, float* __restrict__ outk)
{
    __shared__ float As[16][132];
    __shared__ float Bs[16][68];
    const int t  = threadIdx.x;
    const int mb = blockIdx.x;        // 0..31  rows mb*128
    const int yy = blockIdx.y;        // 0..31
    const int nb = yy & 15;           // head
    const float* __restrict__ W    = (yy < 16) ? Wq  : Wk;
    const float* __restrict__ bias = (yy < 16) ? bq_ : bk_;
    float*                    out  = (yy < 16) ? outq : outk;
    const int tr = t >> 4, tc = t & 15;

    double acc[8][4] = {};

    for (int kt = 0; kt < 1024; kt += 16) {
        #pragma unroll
        for (int i = 0; i < 2; i++) {
            int L   = t + i * 256;
            int row = L >> 2;
            int cg  = (L & 3) * 4;
            float4 a4 = *(const float4*)&A[(size_t)(mb*128 + row)*1024 + kt + cg];
            As[cg+0][row] = a4.x; As[cg+1][row] = a4.y;
            As[cg+2][row] = a4.z; As[cg+3][row] = a4.w;
        }
        {
            int row = t >> 2, cg = (t & 3) * 4;
            float4 b4 = *(const float4*)&W[(size_t)(nb*64 + row)*1024 + kt + cg];
            Bs[cg+0][row] = b4.x; Bs[cg+1][row] = b4.y;
            Bs[cg+2][row] = b4.z; Bs[cg+3][row] = b4.w;
        }
        __syncthreads();
        #pragma unroll
        for (int kk = 0; kk < 16; kk++) {
            float a[8], bv[4];
            *(float4*)&a[0]  = *(const float4*)&As[kk][tr*8];
            *(float4*)&a[4]  = *(const float4*)&As[kk][tr*8+4];
            *(float4*)&bv[0] = *(const float4*)&Bs[kk][tc*4];
            double bd[4] = {(double)bv[0], (double)bv[1], (double)bv[2], (double)bv[3]};
            #pragma unroll
            for (int i = 0; i < 8; i++) {
                double ad = (double)a[i];
                #pragma unroll
                for (int j = 0; j < 4; j++)
                    acc[i][j] = fma(ad, bd[j], acc[i][j]);
            }
        }
        __syncthreads();
    }

    #pragma unroll
    for (int i = 0; i < 8; i++) {
        int token = mb*128 + tr*8 + i;
        int b  = token >> 9, tt = token & 511;
        int c0 = nb*64 + tc*4;
        float4 v;
        v.x = (float)(acc[i][0] + (double)bias[c0+0]);
        v.y = (float)(acc[i][1] + (double)bias[c0+1]);
        v.z = (float)(acc[i][2] + (double)bias[c0+2]);
        v.w = (float)(acc[i][3] + (double)bias[c0+3]);
        *(float4*)&out[(((size_t)b*NHEAD + nb)*TTT + tt)*HDIM + tc*4] = v;
    }
}

// ---------------------------------------------------------------------------
// fp32 GEMM (NT) for V projection (scatter=1) and O projection (scatter=0).
// Round-6 verbatim.
// ---------------------------------------------------------------------------
__global__ __launch_bounds__(256, 2)
void gemm_nt(const float* __restrict__ A, const float* __restrict__ W,
             const float* __restrict__ bias, float* __restrict__ out,
             int scatter)
{
    __shared__ float As[16][132];
    __shared__ float Bs[16][132];
    const int t  = threadIdx.x;
    const int mb = blockIdx.x;
    const int nb = blockIdx.y;
    const int tr = t >> 4, tc = t & 15;

    float acc[8][8] = {};

    for (int kt = 0; kt < 1024; kt += 16) {
        #pragma unroll
        for (int i = 0; i < 2; i++) {
            int L   = t + i * 256;
            int row = L >> 2;
            int cg  = (L & 3) * 4;
            float4 a4 = *(const float4*)&A[(size_t)(mb*128 + row)*1024 + kt + cg];
            As[cg+0][row] = a4.x; As[cg+1][row] = a4.y;
            As[cg+2][row] = a4.z; As[cg+3][row] = a4.w;
            float4 b4 = *(const float4*)&W[(size_t)(nb*128 + row)*1024 + kt + cg];
            Bs[cg+0][row] = b4.x; Bs[cg+1][row] = b4.y;
            Bs[cg+2][row] = b4.z; Bs[cg+3][row] = b4.w;
        }
        __syncthreads();
        #pragma unroll
        for (int kk = 0; kk < 16; kk++) {
            float a[8], bv[8];
            *(float4*)&a[0]  = *(const float4*)&As[kk][tr*8];
            *(float4*)&a[4]  = *(const float4*)&As[kk][tr*8+4];
            *(float4*)&bv[0] = *(const float4*)&Bs[kk][tc*8];
            *(float4*)&bv[4] = *(const float4*)&Bs[kk][tc*8+4];
            #pragma unroll
            for (int i = 0; i < 8; i++)
                #pragma unroll
                for (int j = 0; j < 8; j++)
                    acc[i][j] = fmaf(a[i], bv[j], acc[i][j]);
        }
        __syncthreads();
    }

    if (scatter) {
        #pragma unroll
        for (int i = 0; i < 8; i++) {
            int token = mb*128 + tr*8 + i;
            int b  = token >> 9, tt = token & 511;
            #pragma unroll
            for (int jg = 0; jg < 2; jg++) {
                int c = nb*128 + tc*8 + jg*4;
                int h = c >> 6, d = c & 63;
                float4 v;
                v.x = acc[i][jg*4+0] + bias[c+0];
                v.y = acc[i][jg*4+1] + bias[c+1];
                v.z = acc[i][jg*4+2] + bias[c+2];
                v.w = acc[i][jg*4+3] + bias[c+3];
                *(float4*)&out[(((size_t)b*NHEAD + h)*TTT + tt)*HDIM + d] = v;
            }
        }
    } else {
        #pragma unroll
        for (int i = 0; i < 8; i++) {
            int token = mb*128 + tr*8 + i;
            #pragma unroll
            for (int jg = 0; jg < 2; jg++) {
                int c = nb*128 + tc*8 + jg*4;
                float4 v;
                v.x = acc[i][jg*4+0] + bias[c+0];
                v.y = acc[i][jg*4+1] + bias[c+1];
                v.z = acc[i][jg*4+2] + bias[c+2];
                v.w = acc[i][jg*4+3] + bias[c+3];
                *(float4*)&out[(size_t)token*1024 + c] = v;
            }
        }
    }
}

// ---------------------------------------------------------------------------
// Attention core. Round-8 algorithm (fp32 fast-path scores + eps-guard +
// rare fp64 row fixup) with two codegen fixes:
//  (1) per-row phase FULLY UNROLLED (static indexing of sc[][] — runtime
//      index sent the array to scratch: +136MB WRITE_SIZE, rule #20);
//  (2) launch_bounds(512,6): empirically blocks/CU = w/2 for 512-thr blocks
//      (r6/r7: w=4 -> 2 blocks regardless of LDS; r8: w=2 -> 1 block);
//      w=6 -> 3 blocks/CU, LDS 3x43.5 = 130.5 <= 160 KB fits.
// ---------------------------------------------------------------------------
__global__ __launch_bounds__(512, 6)
void attn_kernel(const float* __restrict__ qb, const float* __restrict__ kb,
                 const float* __restrict__ vb, const float* __restrict__ gates,
                 const float* __restrict__ relb, float* __restrict__ aout)
{
    __shared__ float qs[32][68];                        // 8.7 KB (padded)
    __shared__ union {
        float ks[128][68];                              // 34.8 KB  K-tile [col][d]
        struct { float w[32][64]; unsigned short c[32][64]; } sp;  // 12 KB
    } u;

    const int t    = threadIdx.x;
    const int lane = t & 63, wv = t >> 6;               // 8 waves
    const int qt   = blockIdx.x;        // 0..15
    const int bh   = blockIdx.y;        // 0..127
    const int h    = bh & 15, b = bh >> 4;
    const int qrow_g = qt * 32;
    const int r0   = wv * 4;            // this wave's 4 block-local rows

    const float* qbase = qb + ((size_t)bh*TTT + qrow_g)*HDIM;
    const float* kbase = kb + (size_t)bh*TTT*HDIM;
    const float* vbase = vb + (size_t)bh*TTT*HDIM;

    // ---- load Q tile (32x64) as fp32 ----
    {
        int row = t >> 4, cg = (t & 15) * 4;
        *(float4*)&qs[row][cg] = *(const float4*)&qbase[(size_t)row*HDIM + cg];
    }

    float sc[4][8];                     // scores: sc[i][j] = S[r0+i][lane+64j]

    // ---- scores: 4 K-tiles of 128 cols, fp32 fast path ----
    #pragma unroll
    for (int ktile = 0; ktile < 4; ktile++) {
        __syncthreads();                // protects u.ks (and qs on first iter)
        #pragma unroll
        for (int i = 0; i < 4; i++) {   // stage K tile as [col][d]
            int L   = t + i * 512;
            int col = L >> 4, dg = (L & 15) * 4;
            *(float4*)&u.ks[col][dg] =
                *(const float4*)&kbase[(size_t)(ktile*128 + col)*HDIM + dg];
        }
        __syncthreads();

        float acc[4][2] = {};
        #pragma unroll 4
        for (int d = 0; d < 64; d += 4) {
            float4 k0 = *(const float4*)&u.ks[lane][d];
            float4 k1 = *(const float4*)&u.ks[lane+64][d];
            #pragma unroll
            for (int i = 0; i < 4; i++) {
                float4 q4 = *(const float4*)&qs[r0+i][d];   // broadcast read
                acc[i][0] = fmaf(q4.x, k0.x, acc[i][0]);
                acc[i][0] = fmaf(q4.y, k0.y, acc[i][0]);
                acc[i][0] = fmaf(q4.z, k0.z, acc[i][0]);
                acc[i][0] = fmaf(q4.w, k0.w, acc[i][0]);
                acc[i][1] = fmaf(q4.x, k1.x, acc[i][1]);
                acc[i][1] = fmaf(q4.y, k1.y, acc[i][1]);
                acc[i][1] = fmaf(q4.z, k1.z, acc[i][1]);
                acc[i][1] = fmaf(q4.w, k1.w, acc[i][1]);
            }
        }
        #pragma unroll
        for (int i = 0; i < 4; i++) {
            int rg = qrow_g + r0 + i;
            #pragma unroll
            for (int s01 = 0; s01 < 2; s01++) {
                int c = ktile*128 + lane + 64*s01;
                sc[i][2*ktile+s01] = acc[i][s01]*0.125f +
                                     relb[(size_t)(c - rg + 511)*NHEAD + h];
            }
        }
    }
    __syncthreads();                    // u.ks dead; u.sp may now be written

    // ---- top-32 threshold: 32 extract-max iterations, 4 rows interleaved ----
    float val[4][8];
    #pragma unroll
    for (int i = 0; i < 4; i++)
        #pragma unroll
        for (int j = 0; j < 8; j++) val[i][j] = sc[i][j];

    float rowmax[4], thresh[4];
    #pragma unroll 1
    for (int it = 0; it < TOPK; it++) {
        #pragma unroll
        for (int rr = 0; rr < 4; rr++) {
            float lm = val[rr][0];
            #pragma unroll
            for (int j = 1; j < 8; j++) lm = fmaxf(lm, val[rr][j]);
            float m = lm;
            #pragma unroll
            for (int off = 32; off >= 1; off >>= 1)
                m = fmaxf(m, __shfl_xor(m, off));
            if (it == 0) rowmax[rr] = m;
            thresh[rr] = m;
            unsigned long long ball = __ballot(lm == m);
            int first = __ffsll(ball) - 1;
            if (lane == first) {        // zap exactly one instance of m
                bool done = false;
                #pragma unroll
                for (int j = 0; j < 8; j++)
                    if (!done && val[rr][j] == m) { val[rr][j] = -__builtin_inff(); done = true; }
            }
        }
    }

    // ---- per row (FULLY UNROLLED): eps-guard (+ rare fp64 fixup),
    //      softmax, compaction, sparse PV, store ----
    const float gate = gates[h];
    #pragma unroll
    for (int rr = 0; rr < 4; rr++) {
        const int row = r0 + rr;

        // guard: if any score besides the threshold element itself lies
        // within eps of the threshold, fp32 ranking may differ from fp64.
        int band = 0;
        #pragma unroll
        for (int j = 0; j < 8; j++) {
            bool inb = fabsf(sc[rr][j] - thresh[rr]) <= SCORE_EPS;
            band += __popcll(__ballot(inb));
        }
        if (band >= 2) {
            // ---- fp64 fixup: recompute all 512 scores of this row ----
            int rg = qrow_g + row;
            float fx[8];
            #pragma unroll 1
            for (int j = 0; j < 8; j++) {
                int c = lane + 64*j;
                const float* kc = kbase + (size_t)c*HDIM;
                double a = 0.0;
                #pragma unroll 4
                for (int d = 0; d < 64; d += 4) {
                    float4 kv = *(const float4*)&kc[d];
                    float4 q4 = *(const float4*)&qs[row][d];
                    a = fma((double)q4.x, (double)kv.x, a);
                    a = fma((double)q4.y, (double)kv.y, a);
                    a = fma((double)q4.z, (double)kv.z, a);
                    a = fma((double)q4.w, (double)kv.w, a);
                }
                fx[j] = (float)(a*0.125 +
                        (double)relb[(size_t)(c - rg + 511)*NHEAD + h]);
            }
            #pragma unroll
            for (int j = 0; j < 8; j++) sc[rr][j] = fx[j];
            // redo top-32 for this row on the fp64-grade scores
            float v2[8];
            #pragma unroll
            for (int j = 0; j < 8; j++) v2[j] = sc[rr][j];
            #pragma unroll 1
            for (int it = 0; it < TOPK; it++) {
                float lm = v2[0];
                #pragma unroll
                for (int j = 1; j < 8; j++) lm = fmaxf(lm, v2[j]);
                float m = lm;
                #pragma unroll
                for (int off = 32; off >= 1; off >>= 1)
                    m = fmaxf(m, __shfl_xor(m, off));
                if (it == 0) rowmax[rr] = m;
                thresh[rr] = m;
                unsigned long long ball = __ballot(lm == m);
                int first = __ffsll(ball) - 1;
                if (lane == first) {
                    bool done = false;
                    #pragma unroll
                    for (int j = 0; j < 8; j++)
                        if (!done && v2[j] == m) { v2[j] = -__builtin_inff(); done = true; }
                }
            }
        }

        // ---- softmax weights ----
        float w[8];
        float sum = 0.f;
        #pragma unroll
        for (int j = 0; j < 8; j++) {
            float sv = sc[rr][j];
            float wv2 = (sv >= thresh[rr]) ? __expf(sv - rowmax[rr]) : 0.f;
            w[j] = wv2;
            sum += wv2;
        }
        #pragma unroll
        for (int off = 32; off >= 1; off >>= 1)
            sum += __shfl_xor(sum, off);
        float rscale = gate / sum;

        // ---- compact kept entries (col ascending: j-major, lane-minor) ----
        int n = 0;
        #pragma unroll
        for (int j = 0; j < 8; j++) {
            bool keep = (sc[rr][j] >= thresh[rr]);
            unsigned long long mask = __ballot(keep);
            int pos = n + __popcll(mask & ((1ull << lane) - 1ull));
            if (keep && pos < 64) {
                u.sp.c[row][pos] = (unsigned short)(lane + 64*j);
                u.sp.w[row][pos] = w[j];
            }
            n += __popcll(mask);
        }
        if (n > 64) n = 64;

        // ---- sparse PV: lane == d; entries ascending == k-ascending order ----
        float o = 0.f;
        int e = 0;
        for (; e + 4 <= n; e += 4) {
            int   c0 = u.sp.c[row][e],   c1 = u.sp.c[row][e+1];
            int   c2 = u.sp.c[row][e+2], c3 = u.sp.c[row][e+3];
            float w0 = u.sp.w[row][e],   w1 = u.sp.w[row][e+1];
            float w2 = u.sp.w[row][e+2], w3 = u.sp.w[row][e+3];
            float p0 = vbase[(size_t)c0*HDIM + lane];
            float p1 = vbase[(size_t)c1*HDIM + lane];
            float p2 = vbase[(size_t)c2*HDIM + lane];
            float p3 = vbase[(size_t)c3*HDIM + lane];
            o = fmaf(w0, p0, o);
            o = fmaf(w1, p1, o);
            o = fmaf(w2, p2, o);
            o = fmaf(w3, p3, o);
        }
        for (; e < n; e++) {
            int   c = u.sp.c[row][e];
            float wv2 = u.sp.w[row][e];
            o = fmaf(wv2, vbase[(size_t)c*HDIM + lane], o);
        }

        aout[((size_t)(b*TTT + qrow_g + row))*EMBED + h*HDIM + lane] = o * rscale;
    }
}

// ---------------------------------------------------------------------------
extern "C" void kernel_launch(void* const* d_in, const int* in_sizes, int n_in,
                              void* d_out, int out_size, void* d_ws, size_t ws_size,
                              hipStream_t stream) {
    const float* x     = (const float*)d_in[0];
    const float* Wq    = (const float*)d_in[1];
    const float* bq    = (const float*)d_in[2];
    const float* Wk    = (const float*)d_in[3];
    const float* bk    = (const float*)d_in[4];
    const float* Wv    = (const float*)d_in[5];
    const float* bv    = (const float*)d_in[6];
    const float* Wo    = (const float*)d_in[7];
    const float* bo    = (const float*)d_in[8];
    const float* gates = (const float*)d_in[9];
    const float* relb  = (const float*)d_in[10];
    float* out = (float*)d_out;

    const size_t SZ = (size_t)BT * EMBED;   // 4,194,304 floats
    float* qb = (float*)d_ws;
    float* kb = qb + SZ;
    float* vb = kb + SZ;
    float* ab = vb + SZ;

    gemm_qk_f64<<<dim3(32,32), dim3(256), 0, stream>>>(x, Wq, bq, Wk, bk, qb, kb);
    gemm_nt<<<dim3(32,8), dim3(256), 0, stream>>>(x, Wv, bv, vb, 1);
    attn_kernel<<<dim3(16,128), dim3(512), 0, stream>>>(qb, kb, vb, gates, relb, ab);
    gemm_nt<<<dim3(32,8), dim3(256), 0, stream>>>(ab, Wo, bo, out, 0);
}

// Round 11
// 1105.709 us; speedup vs baseline: 1.5063x; 1.1340x over previous
//
#include <hip/hip_runtime.h>
#include <math.h>

#define EMBED 1024
#define NHEAD 16
#define HDIM  64
#define MAXPOS 512
#define TOPK  32
#define BB    8
#define TTT   512
#define BT    (BB*TTT)   // 4096 tokens
#define SCORE_EPS 1e-4f

// ---------------------------------------------------------------------------
// Q+K projection GEMM, fp64 accumulation. Round-6 verbatim.
// blockIdx.y 0..15 -> Q (Wq,bq,outq), 16..31 -> K (Wk,bk,outk).
// ---------------------------------------------------------------------------
__global__ __launch_bounds__(256, 2)
void gemm_qk_f64(const float* __restrict__ A,
                 const float* __restrict__ Wq, const float* __restrict__ bq_,
                 const float* __restrict__ Wk, const float* __restrict__ bk_,
                 float* __restrict__ outq, float* __restrict__ outk)
{
    __shared__ float As[16][132];
    __shared__ float Bs[16][68];
    const int t  = threadIdx.x;
    const int mb = blockIdx.x;        // 0..31  rows mb*128
    const int yy = blockIdx.y;        // 0..31
    const int nb = yy & 15;           // head
    const float* __restrict__ W    = (yy < 16) ? Wq  : Wk;
    const float* __restrict__ bias = (yy < 16) ? bq_ : bk_;
    float*                    out  = (yy < 16) ? outq : outk;
    const int tr = t >> 4, tc = t & 15;

    double acc[8][4] = {};

    for (int kt = 0; kt < 1024; kt += 16) {
        #pragma unroll
        for (int i = 0; i < 2; i++) {
            int L   = t + i * 256;
            int row = L >> 2;
            int cg  = (L & 3) * 4;
            float4 a4 = *(const float4*)&A[(size_t)(mb*128 + row)*1024 + kt + cg];
            As[cg+0][row] = a4.x; As[cg+1][row] = a4.y;
            As[cg+2][row] = a4.z; As[cg+3][row] = a4.w;
        }
        {
            int row = t >> 2, cg = (t & 3) * 4;
            float4 b4 = *(const float4*)&W[(size_t)(nb*64 + row)*1024 + kt + cg];
            Bs[cg+0][row] = b4.x; Bs[cg+1][row] = b4.y;
            Bs[cg+2][row] = b4.z; Bs[cg+3][row] = b4.w;
        }
        __syncthreads();
        #pragma unroll
        for (int kk = 0; kk < 16; kk++) {
            float a[8], bv[4];
            *(float4*)&a[0]  = *(const float4*)&As[kk][tr*8];
            *(float4*)&a[4]  = *(const float4*)&As[kk][tr*8+4];
            *(float4*)&bv[0] = *(const float4*)&Bs[kk][tc*4];
            double bd[4] = {(double)bv[0], (double)bv[1], (double)bv[2], (double)bv[3]};
            #pragma unroll
            for (int i = 0; i < 8; i++) {
                double ad = (double)a[i];
                #pragma unroll
                for (int j = 0; j < 4; j++)
                    acc[i][j] = fma(ad, bd[j], acc[i][j]);
            }
        }
        __syncthreads();
    }

    #pragma unroll
    for (int i = 0; i < 8; i++) {
        int token = mb*128 + tr*8 + i;
        int b  = token >> 9, tt = token & 511;
        int c0 = nb*64 + tc*4;
        float4 v;
        v.x = (float)(acc[i][0] + (double)bias[c0+0]);
        v.y = (float)(acc[i][1] + (double)bias[c0+1]);
        v.z = (float)(acc[i][2] + (double)bias[c0+2]);
        v.w = (float)(acc[i][3] + (double)bias[c0+3]);
        *(float4*)&out[(((size_t)b*NHEAD + nb)*TTT + tt)*HDIM + tc*4] = v;
    }
}

// ---------------------------------------------------------------------------
// fp32 GEMM (NT) for V projection (scatter=1) and O projection (scatter=0).
// Round-6 verbatim.
// ---------------------------------------------------------------------------
__global__ __launch_bounds__(256, 2)
void gemm_nt(const float* __restrict__ A, const float* __restrict__ W,
             const float* __restrict__ bias, float* __restrict__ out,
             int scatter)
{
    __shared__ float As[16][132];
    __shared__ float Bs[16][132];
    const int t  = threadIdx.x;
    const int mb = blockIdx.x;
    const int nb = blockIdx.y;
    const int tr = t >> 4, tc = t & 15;

    float acc[8][8] = {};

    for (int kt = 0; kt < 1024; kt += 16) {
        #pragma unroll
        for (int i = 0; i < 2; i++) {
            int L   = t + i * 256;
            int row = L >> 2;
            int cg  = (L & 3) * 4;
            float4 a4 = *(const float4*)&A[(size_t)(mb*128 + row)*1024 + kt + cg];
            As[cg+0][row] = a4.x; As[cg+1][row] = a4.y;
            As[cg+2][row] = a4.z; As[cg+3][row] = a4.w;
            float4 b4 = *(const float4*)&W[(size_t)(nb*128 + row)*1024 + kt + cg];
            Bs[cg+0][row] = b4.x; Bs[cg+1][row] = b4.y;
            Bs[cg+2][row] = b4.z; Bs[cg+3][row] = b4.w;
        }
        __syncthreads();
        #pragma unroll
        for (int kk = 0; kk < 16; kk++) {
            float a[8], bv[8];
            *(float4*)&a[0]  = *(const float4*)&As[kk][tr*8];
            *(float4*)&a[4]  = *(const float4*)&As[kk][tr*8+4];
            *(float4*)&bv[0] = *(const float4*)&Bs[kk][tc*8];
            *(float4*)&bv[4] = *(const float4*)&Bs[kk][tc*8+4];
            #pragma unroll
            for (int i = 0; i < 8; i++)
                #pragma unroll
                for (int j = 0; j < 8; j++)
                    acc[i][j] = fmaf(a[i], bv[j], acc[i][j]);
        }
        __syncthreads();
    }

    if (scatter) {
        #pragma unroll
        for (int i = 0; i < 8; i++) {
            int token = mb*128 + tr*8 + i;
            int b  = token >> 9, tt = token & 511;
            #pragma unroll
            for (int jg = 0; jg < 2; jg++) {
                int c = nb*128 + tc*8 + jg*4;
                int h = c >> 6, d = c & 63;
                float4 v;
                v.x = acc[i][jg*4+0] + bias[c+0];
                v.y = acc[i][jg*4+1] + bias[c+1];
                v.z = acc[i][jg*4+2] + bias[c+2];
                v.w = acc[i][jg*4+3] + bias[c+3];
                *(float4*)&out[(((size_t)b*NHEAD + h)*TTT + tt)*HDIM + d] = v;
            }
        }
    } else {
        #pragma unroll
        for (int i = 0; i < 8; i++) {
            int token = mb*128 + tr*8 + i;
            #pragma unroll
            for (int jg = 0; jg < 2; jg++) {
                int c = nb*128 + tc*8 + jg*4;
                float4 v;
                v.x = acc[i][jg*4+0] + bias[c+0];
                v.y = acc[i][jg*4+1] + bias[c+1];
                v.z = acc[i][jg*4+2] + bias[c+2];
                v.w = acc[i][jg*4+3] + bias[c+3];
                *(float4*)&out[(size_t)token*1024 + c] = v;
            }
        }
    }
}

// ---------------------------------------------------------------------------
// Attention core. ROUND-9 VERBATIM except ONE change (strict bisect of r10):
// the main-path top-32 threshold uses a ballot-radix select on sortable uint
// keys (exact integer arithmetic -> identical 32nd-largest value) instead of
// the 32-iteration extract-max. This removes the val[4][8] register copy
// (the spill source at the (512,6) cap) and all LDS-shuffle traffic in the
// select. K-tile layout, fp32 fast path, eps-guard, fp64 fixup (with its
// original extract-max), softmax, compaction, PV: all round-9 verbatim.
// ---------------------------------------------------------------------------
__global__ __launch_bounds__(512, 6)
void attn_kernel(const float* __restrict__ qb, const float* __restrict__ kb,
                 const float* __restrict__ vb, const float* __restrict__ gates,
                 const float* __restrict__ relb, float* __restrict__ aout)
{
    __shared__ float qs[32][68];                        // 8.7 KB (padded)
    __shared__ union {
        float ks[128][68];                              // 34.8 KB  K-tile [col][d]
        struct { float w[32][64]; unsigned short c[32][64]; } sp;  // 12 KB
    } u;

    const int t    = threadIdx.x;
    const int lane = t & 63, wv = t >> 6;               // 8 waves
    const int qt   = blockIdx.x;        // 0..15
    const int bh   = blockIdx.y;        // 0..127
    const int h    = bh & 15, b = bh >> 4;
    const int qrow_g = qt * 32;
    const int r0   = wv * 4;            // this wave's 4 block-local rows

    const float* qbase = qb + ((size_t)bh*TTT + qrow_g)*HDIM;
    const float* kbase = kb + (size_t)bh*TTT*HDIM;
    const float* vbase = vb + (size_t)bh*TTT*HDIM;

    // ---- load Q tile (32x64) as fp32 ----
    {
        int row = t >> 4, cg = (t & 15) * 4;
        *(float4*)&qs[row][cg] = *(const float4*)&qbase[(size_t)row*HDIM + cg];
    }

    float sc[4][8];                     // scores: sc[i][j] = S[r0+i][lane+64j]

    // ---- scores: 4 K-tiles of 128 cols, fp32 fast path (r9 verbatim) ----
    #pragma unroll
    for (int ktile = 0; ktile < 4; ktile++) {
        __syncthreads();                // protects u.ks (and qs on first iter)
        #pragma unroll
        for (int i = 0; i < 4; i++) {   // stage K tile as [col][d]
            int L   = t + i * 512;
            int col = L >> 4, dg = (L & 15) * 4;
            *(float4*)&u.ks[col][dg] =
                *(const float4*)&kbase[(size_t)(ktile*128 + col)*HDIM + dg];
        }
        __syncthreads();

        float acc[4][2] = {};
        #pragma unroll 4
        for (int d = 0; d < 64; d += 4) {
            float4 k0 = *(const float4*)&u.ks[lane][d];
            float4 k1 = *(const float4*)&u.ks[lane+64][d];
            #pragma unroll
            for (int i = 0; i < 4; i++) {
                float4 q4 = *(const float4*)&qs[r0+i][d];   // broadcast read
                acc[i][0] = fmaf(q4.x, k0.x, acc[i][0]);
                acc[i][0] = fmaf(q4.y, k0.y, acc[i][0]);
                acc[i][0] = fmaf(q4.z, k0.z, acc[i][0]);
                acc[i][0] = fmaf(q4.w, k0.w, acc[i][0]);
                acc[i][1] = fmaf(q4.x, k1.x, acc[i][1]);
                acc[i][1] = fmaf(q4.y, k1.y, acc[i][1]);
                acc[i][1] = fmaf(q4.z, k1.z, acc[i][1]);
                acc[i][1] = fmaf(q4.w, k1.w, acc[i][1]);
            }
        }
        #pragma unroll
        for (int i = 0; i < 4; i++) {
            int rg = qrow_g + r0 + i;
            #pragma unroll
            for (int s01 = 0; s01 < 2; s01++) {
                int c = ktile*128 + lane + 64*s01;
                sc[i][2*ktile+s01] = acc[i][s01]*0.125f +
                                     relb[(size_t)(c - rg + 511)*NHEAD + h];
            }
        }
    }
    __syncthreads();                    // u.ks dead; u.sp may now be written

    // ---- per row (FULLY UNROLLED): radix top-32 + rowmax, eps-guard
    //      (+ r9's fp64 fixup with extract-max), softmax, compaction, PV ----
    const float gate = gates[h];
    float rowmax[4], thresh[4];
    #pragma unroll
    for (int rr = 0; rr < 4; rr++) {
        const int row = r0 + rr;

        // ---- rowmax via butterfly (needed for softmax) ----
        {
            float m = sc[rr][0];
            #pragma unroll
            for (int j = 1; j < 8; j++) m = fmaxf(m, sc[rr][j]);
            #pragma unroll
            for (int off = 32; off >= 1; off >>= 1)
                m = fmaxf(m, __shfl_xor(m, off));
            rowmax[rr] = m;
        }

        // ---- radix select: exact 32nd-largest score (sortable uint keys) ----
        {
            unsigned int sk[8];
            #pragma unroll
            for (int j = 0; j < 8; j++) {
                unsigned int uu = __float_as_uint(sc[rr][j]);
                sk[j] = ((int)uu < 0) ? ~uu : (uu | 0x80000000u);
            }
            unsigned int p = 0u;
            #pragma unroll 1
            for (int bit = 31; bit >= 0; --bit) {
                unsigned int cnd = p | (1u << bit);
                int cnt = 0;
                #pragma unroll
                for (int j = 0; j < 8; j++)
                    cnt += __popcll(__ballot(sk[j] >= cnd));
                if (cnt >= TOPK) p = cnd;
            }
            thresh[rr] = (p >= 0x80000000u) ? __uint_as_float(p & 0x7fffffffu)
                                            : __uint_as_float(~p);
        }

        // ---- eps-guard: ambiguity near the threshold -> fp64 fixup (r9) ----
        int band = 0;
        #pragma unroll
        for (int j = 0; j < 8; j++) {
            bool inb = fabsf(sc[rr][j] - thresh[rr]) <= SCORE_EPS;
            band += __popcll(__ballot(inb));
        }
        if (band >= 2) {
            // ---- fp64 fixup: recompute all 512 scores of this row ----
            int rg = qrow_g + row;
            float fx[8];
            #pragma unroll 1
            for (int j = 0; j < 8; j++) {
                int c = lane + 64*j;
                const float* kc = kbase + (size_t)c*HDIM;
                double a = 0.0;
                #pragma unroll 4
                for (int d = 0; d < 64; d += 4) {
                    float4 kv = *(const float4*)&kc[d];
                    float4 q4 = *(const float4*)&qs[row][d];
                    a = fma((double)q4.x, (double)kv.x, a);
                    a = fma((double)q4.y, (double)kv.y, a);
                    a = fma((double)q4.z, (double)kv.z, a);
                    a = fma((double)q4.w, (double)kv.w, a);
                }
                fx[j] = (float)(a*0.125 +
                        (double)relb[(size_t)(c - rg + 511)*NHEAD + h]);
            }
            #pragma unroll
            for (int j = 0; j < 8; j++) sc[rr][j] = fx[j];
            // redo top-32 for this row (r9's extract-max, verbatim)
            float v2[8];
            #pragma unroll
            for (int j = 0; j < 8; j++) v2[j] = sc[rr][j];
            #pragma unroll 1
            for (int it = 0; it < TOPK; it++) {
                float lm = v2[0];
                #pragma unroll
                for (int j = 1; j < 8; j++) lm = fmaxf(lm, v2[j]);
                float m = lm;
                #pragma unroll
                for (int off = 32; off >= 1; off >>= 1)
                    m = fmaxf(m, __shfl_xor(m, off));
                if (it == 0) rowmax[rr] = m;
                thresh[rr] = m;
                unsigned long long ball = __ballot(lm == m);
                int first = __ffsll(ball) - 1;
                if (lane == first) {
                    bool done = false;
                    #pragma unroll
                    for (int j = 0; j < 8; j++)
                        if (!done && v2[j] == m) { v2[j] = -__builtin_inff(); done = true; }
                }
            }
        }

        // ---- softmax weights (r9 verbatim) ----
        float w[8];
        float sum = 0.f;
        #pragma unroll
        for (int j = 0; j < 8; j++) {
            float sv = sc[rr][j];
            float wv2 = (sv >= thresh[rr]) ? __expf(sv - rowmax[rr]) : 0.f;
            w[j] = wv2;
            sum += wv2;
        }
        #pragma unroll
        for (int off = 32; off >= 1; off >>= 1)
            sum += __shfl_xor(sum, off);
        float rscale = gate / sum;

        // ---- compact kept entries (r9 verbatim) ----
        int n = 0;
        #pragma unroll
        for (int j = 0; j < 8; j++) {
            bool keep = (sc[rr][j] >= thresh[rr]);
            unsigned long long mask = __ballot(keep);
            int pos = n + __popcll(mask & ((1ull << lane) - 1ull));
            if (keep && pos < 64) {
                u.sp.c[row][pos] = (unsigned short)(lane + 64*j);
                u.sp.w[row][pos] = w[j];
            }
            n += __popcll(mask);
        }
        if (n > 64) n = 64;

        // ---- sparse PV (r9 verbatim) ----
        float o = 0.f;
        int e = 0;
        for (; e + 4 <= n; e += 4) {
            int   c0 = u.sp.c[row][e],   c1 = u.sp.c[row][e+1];
            int   c2 = u.sp.c[row][e+2], c3 = u.sp.c[row][e+3];
            float w0 = u.sp.w[row][e],   w1 = u.sp.w[row][e+1];
            float w2 = u.sp.w[row][e+2], w3 = u.sp.w[row][e+3];
            float p0 = vbase[(size_t)c0*HDIM + lane];
            float p1 = vbase[(size_t)c1*HDIM + lane];
            float p2 = vbase[(size_t)c2*HDIM + lane];
            float p3 = vbase[(size_t)c3*HDIM + lane];
            o = fmaf(w0, p0, o);
            o = fmaf(w1, p1, o);
            o = fmaf(w2, p2, o);
            o = fmaf(w3, p3, o);
        }
        for (; e < n; e++) {
            int   c = u.sp.c[row][e];
            float wv2 = u.sp.w[row][e];
            o = fmaf(wv2, vbase[(size_t)c*HDIM + lane], o);
        }

        aout[((size_t)(b*TTT + qrow_g + row))*EMBED + h*HDIM + lane] = o * rscale;
    }
}

// ---------------------------------------------------------------------------
extern "C" void kernel_launch(void* const* d_in, const int* in_sizes, int n_in,
                              void* d_out, int out_size, void* d_ws, size_t ws_size,
                              hipStream_t stream) {
    const float* x     = (const float*)d_in[0];
    const float* Wq    = (const float*)d_in[1];
    const float* bq    = (const float*)d_in[2];
    const float* Wk    = (const float*)d_in[3];
    const float* bk    = (const float*)d_in[4];
    const float* Wv    = (const float*)d_in[5];
    const float* bv    = (const float*)d_in[6];
    const float* Wo    = (const float*)d_in[7];
    const float* bo    = (const float*)d_in[8];
    const float* gates = (const float*)d_in[9];
    const float* relb  = (const float*)d_in[10];
    float* out = (float*)d_out;

    const size_t SZ = (size_t)BT * EMBED;   // 4,194,304 floats
    float* qb = (float*)d_ws;
    float* kb = qb + SZ;
    float* vb = kb + SZ;
    float* ab = vb + SZ;

    gemm_qk_f64<<<dim3(32,32), dim3(256), 0, stream>>>(x, Wq, bq, Wk, bk, qb, kb);
    gemm_nt<<<dim3(32,8), dim3(256), 0, stream>>>(x, Wv, bv, vb, 1);
    attn_kernel<<<dim3(16,128), dim3(512), 0, stream>>>(qb, kb, vb, gates, relb, ab);
    gemm_nt<<<dim3(32,8), dim3(256), 0, stream>>>(ab, Wo, bo, out, 0);
}